// Round 9
// baseline (176.596 us; speedup 1.0000x reference)
//
#include <hip/hip_runtime.h>
#include <hip/hip_bf16.h>
#include <stdint.h>

// Problem constants
constexpr int cB = 2;
constexpr int cS = 2048;
constexpr int cH = 1024;
constexpr int cNH = 16;
constexpr int cHD = 64;
constexpr int cBS = cB * cS;  // 4096

typedef short short8 __attribute__((ext_vector_type(8)));
typedef short short4v __attribute__((ext_vector_type(4)));
typedef float f32x4 __attribute__((ext_vector_type(4)));
typedef unsigned uint2v __attribute__((ext_vector_type(2)));

__device__ inline unsigned short f2bf(float f) {
  union { float f; unsigned u; } v; v.f = f;
  unsigned r = v.u + 0x7FFF + ((v.u >> 16) & 1);  // RNE
  return (unsigned short)(r >> 16);
}

// pack 2 f32 -> 2 bf16 (RNE) in one instruction
__device__ inline unsigned cvtpk(float a, float b) {
  unsigned r;
  asm("v_cvt_pk_bf16_f32 %0, %1, %2" : "=v"(r) : "v"(a), "v"(b));
  return r;
}

__device__ inline void gload_lds16(const void* g, void* l) {
  __builtin_amdgcn_global_load_lds(
      (const __attribute__((address_space(1))) void*)g,
      (__attribute__((address_space(3))) void*)l,
      16, 0, 0);
}

// ds_read_b64_tr_b16 (verified r7): each lane does a plain 64b read (4
// consecutive bf16) at its OWN addr; HW transposes within each 16-lane
// group: the group's reads form a 4x16 tile T (lane s supplies
// T[s>>2][(s&3)*4..+4)); lane a receives column a (elem j = T[j][a]).
__device__ inline short4v tr16(const unsigned short* p) {
  short4v d;
  auto p3 = (const __attribute__((address_space(3))) unsigned short*)p;
  asm volatile("ds_read_b64_tr_b16 %0, %1" : "=v"(d) : "v"(p3) : "memory");
  return d;
}

// ---------------- QKV GEMM: C[i,o] = sum_k X[i,k] * W[o,k] + b[o] ----------------
// fp32 inputs, bf16 output (Q/K/V scratch). Reg-staged LDS (f32x4 -> bf16 -> ds_write).
// 128x128 tile, BK=32, 4 waves (2x2), each wave 64x64 (4x4 MFMA frags).
constexpr int BM = 128, BN = 128, BK = 32;

__global__ __launch_bounds__(256) void qkv_gemm(
    const float* __restrict__ X,   // [4096][1024]
    const float* __restrict__ Wq,  // [1024][1024] (row=out, col=in)
    const float* __restrict__ Wk,
    const float* __restrict__ Wv,
    const float* __restrict__ bq, const float* __restrict__ bk,
    const float* __restrict__ bv,
    unsigned short* __restrict__ Qb, unsigned short* __restrict__ Kb,
    unsigned short* __restrict__ Vb) {
  __shared__ alignas(16) unsigned short As[BM * BK];  // [128][32]
  __shared__ alignas(16) unsigned short Bs[BN * BK];

  const int nb = blockIdx.x;  // 0..23
  const int mb = blockIdx.y;  // 0..31
  const int m0 = mb * BM;
  const int wsel = nb >> 3;
  const int n0 = (nb & 7) * BN;  // col within this W's 1024
  const float* W = (wsel == 0) ? Wq : (wsel == 1 ? Wk : Wv);
  const float* bias = (wsel == 0) ? bq : (wsel == 1 ? bk : bv);
  unsigned short* Out = (wsel == 0) ? Qb : (wsel == 1 ? Kb : Vb);

  const int t = threadIdx.x;
  const int w = t >> 6, l = t & 63, lr = l & 15, lg = l >> 4;
  const int wm = w >> 1, wn = w & 1;
  const int srow = t >> 1;
  const int scol = (t & 1) * 16;

  f32x4 acc[4][4];
#pragma unroll
  for (int mi = 0; mi < 4; ++mi)
#pragma unroll
    for (int ni = 0; ni < 4; ++ni) acc[mi][ni] = {0.f, 0.f, 0.f, 0.f};

  for (int kt = 0; kt < cH / BK; ++kt) {
    const int k0 = kt * BK;
    __syncthreads();
    {
      const float* s = X + (size_t)(m0 + srow) * cH + k0 + scol;
      f32x4 v0 = *reinterpret_cast<const f32x4*>(s);
      f32x4 v1 = *reinterpret_cast<const f32x4*>(s + 4);
      f32x4 v2 = *reinterpret_cast<const f32x4*>(s + 8);
      f32x4 v3 = *reinterpret_cast<const f32x4*>(s + 12);
      short8 o0, o1;
#pragma unroll
      for (int j = 0; j < 4; ++j) {
        o0[j] = (short)f2bf(v0[j]);
        o0[4 + j] = (short)f2bf(v1[j]);
        o1[j] = (short)f2bf(v2[j]);
        o1[4 + j] = (short)f2bf(v3[j]);
      }
      *reinterpret_cast<short8*>(&As[srow * BK + scol]) = o0;
      *reinterpret_cast<short8*>(&As[srow * BK + scol + 8]) = o1;
    }
    {
      const float* s = W + (size_t)(n0 + srow) * cH + k0 + scol;
      f32x4 v0 = *reinterpret_cast<const f32x4*>(s);
      f32x4 v1 = *reinterpret_cast<const f32x4*>(s + 4);
      f32x4 v2 = *reinterpret_cast<const f32x4*>(s + 8);
      f32x4 v3 = *reinterpret_cast<const f32x4*>(s + 12);
      short8 o0, o1;
#pragma unroll
      for (int j = 0; j < 4; ++j) {
        o0[j] = (short)f2bf(v0[j]);
        o0[4 + j] = (short)f2bf(v1[j]);
        o1[j] = (short)f2bf(v2[j]);
        o1[4 + j] = (short)f2bf(v3[j]);
      }
      *reinterpret_cast<short8*>(&Bs[srow * BK + scol]) = o0;
      *reinterpret_cast<short8*>(&Bs[srow * BK + scol + 8]) = o1;
    }
    __syncthreads();

    short8 af[4], bfr[4];
#pragma unroll
    for (int mi = 0; mi < 4; ++mi)
      af[mi] = *reinterpret_cast<const short8*>(
          &As[(wm * 64 + mi * 16 + lr) * BK + lg * 8]);
#pragma unroll
    for (int ni = 0; ni < 4; ++ni)
      bfr[ni] = *reinterpret_cast<const short8*>(
          &Bs[(wn * 64 + ni * 16 + lr) * BK + lg * 8]);
#pragma unroll
    for (int mi = 0; mi < 4; ++mi)
#pragma unroll
      for (int ni = 0; ni < 4; ++ni)
        acc[mi][ni] = __builtin_amdgcn_mfma_f32_16x16x32_bf16(
            af[mi], bfr[ni], acc[mi][ni], 0, 0, 0);
  }

#pragma unroll
  for (int ni = 0; ni < 4; ++ni) {
    const int col = n0 + wn * 64 + ni * 16 + lr;
    const float bvv = bias[col];
#pragma unroll
    for (int mi = 0; mi < 4; ++mi) {
      const int row = m0 + wm * 64 + mi * 16 + lg * 4;
#pragma unroll
      for (int r = 0; r < 4; ++r)
        Out[(size_t)(row + r) * cH + col] = f2bf(acc[mi][ni][r] + bvv);
    }
  }
}

// ---------------- Flash attention ----------------
// Block = (qb, bh): 64 q-rows of one (b,h). 4 waves x 16 q-rows each.
// K/V tiles (64x64) staged once per block into double-buffered LDS (r7).
// r8: row-sum via MFMA(pa, ones); transposed P pT[64][16] per wave; 1 barrier.
// r9: wave-shared softmax max (max over the wave's 16 q-rows; ratio-exact),
//     defer-rescale THR=8 (uniform branch), cvt_pk P-pack, setprio on PV.
__global__ __launch_bounds__(256) void attn_kernel(
    const unsigned short* __restrict__ Qb,  // [B*S][H] bf16
    const unsigned short* __restrict__ Kb,
    const unsigned short* __restrict__ Vb,
    const float* __restrict__ mask,         // [B][S]
    float* __restrict__ out) {              // [B*S][H] fp32
  __shared__ alignas(16) unsigned short Ks[2][64 * 64];    // 16 KB
  __shared__ alignas(16) unsigned short Vs[2][64 * 64];    // 16 KB
  __shared__ alignas(16) unsigned short plds[4][64 * 16];  // 8 KB, per-wave pT

  const int qb = blockIdx.x;  // 0..31
  const int bh = blockIdx.y;  // 0..31
  const int b = bh >> 4, h = bh & 15;
  const int t = threadIdx.x;
  const int w = t >> 6, l = t & 63, lr = l & 15, lg = l >> 4;
  const int q0 = qb * 64 + w * 16;

  const unsigned short* Kbase = Kb + (size_t)b * cS * cH + h * cHD;
  const unsigned short* Vbase = Vb + (size_t)b * cS * cH + h * cHD;
  const float* mbase = mask + b * cS;

  // Staging decode (r7-verified).
  int rK[2], cK[2], rV[2], cV[2];
#pragma unroll
  for (int s2 = 0; s2 < 2; ++s2) {
    const int g = (w * 2 + s2) * 64 + l;
    const int gr = g >> 3, gc = g & 7;
    rK[s2] = gr;
    cK[s2] = (gc ^ (gr & 7)) * 8;
    rV[s2] = (gr >> 2) * 4 + (gc >> 1);
    cV[s2] = (gr & 3) * 16 + (gc & 1) * 8;
  }

  const unsigned short* Qrow = Qb + (size_t)(b * cS + q0 + lr) * cH + h * cHD;
  short8 qf0 = *reinterpret_cast<const short8*>(Qrow + lg * 8);
  short8 qf1 = *reinterpret_cast<const short8*>(Qrow + 32 + lg * 8);

  // ones B-frag (bf16 1.0 = 0x3F80) for the row-sum MFMA
  short8 ones;
#pragma unroll
  for (int j = 0; j < 8; ++j) ones[j] = (short)0x3F80;

  f32x4 oacc[4];
#pragma unroll
  for (int d16 = 0; d16 < 4; ++d16) oacc[d16] = {0.f, 0.f, 0.f, 0.f};
  f32x4 osum = {0.f, 0.f, 0.f, 0.f};
  float mrow = -1e30f;  // wave-shared running max (uniform)

  auto stage = [&](int bufi, int kv0) {
#pragma unroll
    for (int s2 = 0; s2 < 2; ++s2) {
      gload_lds16(Kbase + (size_t)(kv0 + rK[s2]) * cH + cK[s2],
                  (char*)&Ks[bufi][0] + (w * 2 + s2) * 1024);
      gload_lds16(Vbase + (size_t)(kv0 + rV[s2]) * cH + cV[s2],
                  (char*)&Vs[bufi][0] + (w * 2 + s2) * 1024);
    }
  };

  stage(0, 0);
  asm volatile("s_waitcnt vmcnt(0)" ::: "memory");
  __syncthreads();

  unsigned short* pw = &plds[w][0];  // pT[64][16] (swizzled)

  constexpr int NT = cS / 64;  // 32
  for (int kt = 0; kt < NT; ++kt) {
    const int bufi = kt & 1;
    if (kt + 1 < NT) stage(bufi ^ 1, (kt + 1) * 64);

    const unsigned short* Kt = &Ks[bufi][0];
    const unsigned short* Vt = &Vs[bufi][0];
    const int kv0 = kt * 64;

    // ---- QK^T from swizzled K LDS ----
    f32x4 sc[4];
#pragma unroll
    for (int n = 0; n < 4; ++n) {
      const int kr = n * 16 + lr;
      const unsigned sw = (unsigned)((kr & 7) << 4);
      const unsigned b0 = ((unsigned)(kr * 128 + lg * 16)) ^ sw;
      const unsigned b1 = ((unsigned)(kr * 128 + 64 + lg * 16)) ^ sw;
      short8 kf0 = *reinterpret_cast<const short8*>((const char*)Kt + b0);
      short8 kf1 = *reinterpret_cast<const short8*>((const char*)Kt + b1);
      f32x4 z = {0.f, 0.f, 0.f, 0.f};
      z = __builtin_amdgcn_mfma_f32_16x16x32_bf16(qf0, kf0, z, 0, 0, 0);
      z = __builtin_amdgcn_mfma_f32_16x16x32_bf16(qf1, kf1, z, 0, 0, 0);
      sc[n] = z * 0.125f + mbase[kv0 + kr];
    }

    // ---- wave-shared max (single value for the wave's 16 q-rows) ----
    f32x4 m4;
#pragma unroll
    for (int c = 0; c < 4; ++c)
      m4[c] = fmaxf(fmaxf(sc[0][c], sc[1][c]), fmaxf(sc[2][c], sc[3][c]));
    float mx = fmaxf(fmaxf(m4[0], m4[1]), fmaxf(m4[2], m4[3]));
#pragma unroll
    for (int d = 1; d < 64; d <<= 1) mx = fmaxf(mx, __shfl_xor(mx, d));

    // ---- defer-rescale (uniform branch, THR=8): P bounded by e^8 ----
    if (mx - mrow > 8.0f) {
      const float scalef = __expf(mrow - mx);
      mrow = mx;
#pragma unroll
      for (int d16 = 0; d16 < 4; ++d16) oacc[d16] *= scalef;
      osum *= scalef;
    }

    // ---- P = exp(sc - mrow), pack via cvt_pk, write P^T [64][16] swizzled ----
    const int pcb = (lg ^ (lr >> 2)) * 4;
#pragma unroll
    for (int n = 0; n < 4; ++n) {
      const float p0 = __expf(sc[n][0] - mrow);
      const float p1 = __expf(sc[n][1] - mrow);
      const float p2 = __expf(sc[n][2] - mrow);
      const float p3 = __expf(sc[n][3] - mrow);
      uint2v u = {cvtpk(p0, p1), cvtpk(p2, p3)};
      *reinterpret_cast<uint2v*>(&pw[(n * 16 + lr) * 16 + pcb]) = u;
    }
    asm volatile("s_waitcnt lgkmcnt(0)" ::: "memory");
    __builtin_amdgcn_sched_barrier(0);

    // ---- PV: A = P via tr16 on pT, B = V via tr16 (r7-verified) ----
#pragma unroll
    for (int ks2 = 0; ks2 < 2; ++ks2) {
      const int k0 = ks2 * 32 + lg * 8;
      const int key = (lg & 1) * 2;  // ((k0+j)>>2)&3 for j=0..3
      short4v t0 = tr16(&pw[(k0 + (lr >> 2)) * 16 + (((lr & 3) ^ key) * 4)]);
      short4v t1 =
          tr16(&pw[(k0 + 4 + (lr >> 2)) * 16 + (((lr & 3) ^ key ^ 1) * 4)]);
      short4v tv[8];
#pragma unroll
      for (int d16 = 0; d16 < 4; ++d16) {
        const unsigned short* a0 =
            Vt + (ks2 * 8 + lg * 2) * 256 + d16 * 64 + lr * 4;
        tv[2 * d16] = tr16(a0);            // V rows k0..+3, col lr
        tv[2 * d16 + 1] = tr16(a0 + 256);  // V rows k0+4..+7, col lr
      }
      asm volatile("s_waitcnt lgkmcnt(0)" ::: "memory");
      __builtin_amdgcn_sched_barrier(0);
      short8 pa;
#pragma unroll
      for (int j = 0; j < 4; ++j) {
        pa[j] = t0[j];
        pa[4 + j] = t1[j];
      }
      __builtin_amdgcn_s_setprio(1);
      osum = __builtin_amdgcn_mfma_f32_16x16x32_bf16(pa, ones, osum, 0, 0, 0);
#pragma unroll
      for (int d16 = 0; d16 < 4; ++d16) {
        short8 vf;
#pragma unroll
        for (int j = 0; j < 4; ++j) {
          vf[j] = tv[2 * d16][j];
          vf[4 + j] = tv[2 * d16 + 1][j];
        }
        oacc[d16] =
            __builtin_amdgcn_mfma_f32_16x16x32_bf16(pa, vf, oacc[d16], 0, 0, 0);
      }
      __builtin_amdgcn_s_setprio(0);
    }

    asm volatile("s_waitcnt vmcnt(0)" ::: "memory");
    __syncthreads();  // staged tile kt+1 ready; all waves done with buf kt
  }

  // fp32 store; denominator from the MFMA row-sum accumulator
  float* obase = out + (size_t)(b * cS + q0 + lg * 4) * cH + h * cHD;
#pragma unroll
  for (int r = 0; r < 4; ++r) {
    const float inv = 1.0f / osum[r];
#pragma unroll
    for (int d16 = 0; d16 < 4; ++d16)
      obase[(size_t)r * cH + d16 * 16 + lr] = oacc[d16][r] * inv;
  }
}

// ---------------- launcher ----------------
extern "C" void kernel_launch(void* const* d_in, const int* in_sizes, int n_in,
                              void* d_out, int out_size, void* d_ws,
                              size_t ws_size, hipStream_t stream) {
  const float* X = (const float*)d_in[0];     // [B,S,H]
  const float* mask = (const float*)d_in[1];  // [B,1,1,S]
  const float* Wq = (const float*)d_in[2];
  const float* bq = (const float*)d_in[3];
  const float* Wk = (const float*)d_in[4];
  const float* bk = (const float*)d_in[5];
  const float* Wv = (const float*)d_in[6];
  const float* bv = (const float*)d_in[7];
  float* outp = (float*)d_out;  // fp32 (reference output dtype)

  // workspace: Q,K,V bf16 -> 24 MB total
  char* ws = (char*)d_ws;
  const size_t MB = 1 << 20;
  unsigned short* Qb = (unsigned short*)(ws + 0 * MB);   // 8 MB
  unsigned short* Kb = (unsigned short*)(ws + 8 * MB);   // 8 MB
  unsigned short* Vb = (unsigned short*)(ws + 16 * MB);  // 8 MB

  qkv_gemm<<<dim3(24, 32), 256, 0, stream>>>(X, Wq, Wk, Wv, bq, bk, bv, Qb, Kb,
                                             Vb);
  attn_kernel<<<dim3(32, 32), 256, 0, stream>>>(Qb, Kb, Vb, mask, outp);
}

// Round 10
// 165.672 us; speedup vs baseline: 1.0659x; 1.0659x over previous
//
#include <hip/hip_runtime.h>
#include <hip/hip_bf16.h>
#include <stdint.h>

// Problem constants
constexpr int cB = 2;
constexpr int cS = 2048;
constexpr int cH = 1024;
constexpr int cNH = 16;
constexpr int cHD = 64;
constexpr int cBS = cB * cS;  // 4096

typedef short short8 __attribute__((ext_vector_type(8)));
typedef short short4v __attribute__((ext_vector_type(4)));
typedef float f32x4 __attribute__((ext_vector_type(4)));

// HW bf16 convert (RNE); 1 VALU op, pair-fusible to v_cvt_pk_bf16_f32 by the
// compiler (m240: scalar casts beat hand-written cvt_pk asm).
__device__ inline unsigned short f2bf(float f) {
  __hip_bfloat16 h = __float2bfloat16(f);
  return __builtin_bit_cast(unsigned short, h);
}

__device__ inline void gload_lds16(const void* g, void* l) {
  __builtin_amdgcn_global_load_lds(
      (const __attribute__((address_space(1))) void*)g,
      (__attribute__((address_space(3))) void*)l,
      16, 0, 0);
}

// ds_read_b64_tr_b16 (verified r7): each lane does a plain 64b read (4
// consecutive bf16) at its OWN addr; HW transposes within each 16-lane
// group: the group's reads form a 4x16 tile T (lane s supplies
// T[s>>2][(s&3)*4..+4)); lane a receives column a (elem j = T[j][a]).
__device__ inline short4v tr16(const unsigned short* p) {
  short4v d;
  auto p3 = (const __attribute__((address_space(3))) unsigned short*)p;
  asm volatile("ds_read_b64_tr_b16 %0, %1" : "=v"(d) : "v"(p3) : "memory");
  return d;
}

// ---------------- QKV GEMM: C[i,o] = sum_k X[i,k] * W[o,k] + b[o] ----------------
// fp32 inputs, bf16 output (Q/K/V scratch). Reg-staged LDS (f32x4 -> bf16 -> ds_write).
// 128x128 tile, BK=32, 4 waves (2x2), each wave 64x64 (4x4 MFMA frags).
// Q output is pre-scaled by 0.125 (=1/sqrt(HD); exact power-of-2).
constexpr int BM = 128, BN = 128, BK = 32;

__global__ __launch_bounds__(256) void qkv_gemm(
    const float* __restrict__ X,   // [4096][1024]
    const float* __restrict__ Wq,  // [1024][1024] (row=out, col=in)
    const float* __restrict__ Wk,
    const float* __restrict__ Wv,
    const float* __restrict__ bq, const float* __restrict__ bk,
    const float* __restrict__ bv,
    unsigned short* __restrict__ Qb, unsigned short* __restrict__ Kb,
    unsigned short* __restrict__ Vb) {
  __shared__ alignas(16) unsigned short As[BM * BK];  // [128][32]
  __shared__ alignas(16) unsigned short Bs[BN * BK];

  const int nb = blockIdx.x;  // 0..23
  const int mb = blockIdx.y;  // 0..31
  const int m0 = mb * BM;
  const int wsel = nb >> 3;
  const int n0 = (nb & 7) * BN;  // col within this W's 1024
  const float* W = (wsel == 0) ? Wq : (wsel == 1 ? Wk : Wv);
  const float* bias = (wsel == 0) ? bq : (wsel == 1 ? bk : bv);
  unsigned short* Out = (wsel == 0) ? Qb : (wsel == 1 ? Kb : Vb);
  const float oscale = (wsel == 0) ? 0.125f : 1.0f;

  const int t = threadIdx.x;
  const int w = t >> 6, l = t & 63, lr = l & 15, lg = l >> 4;
  const int wm = w >> 1, wn = w & 1;
  const int srow = t >> 1;
  const int scol = (t & 1) * 16;

  f32x4 acc[4][4];
#pragma unroll
  for (int mi = 0; mi < 4; ++mi)
#pragma unroll
    for (int ni = 0; ni < 4; ++ni) acc[mi][ni] = {0.f, 0.f, 0.f, 0.f};

  for (int kt = 0; kt < cH / BK; ++kt) {
    const int k0 = kt * BK;
    __syncthreads();
    {
      const float* s = X + (size_t)(m0 + srow) * cH + k0 + scol;
      f32x4 v0 = *reinterpret_cast<const f32x4*>(s);
      f32x4 v1 = *reinterpret_cast<const f32x4*>(s + 4);
      f32x4 v2 = *reinterpret_cast<const f32x4*>(s + 8);
      f32x4 v3 = *reinterpret_cast<const f32x4*>(s + 12);
      short8 o0, o1;
#pragma unroll
      for (int j = 0; j < 4; ++j) {
        o0[j] = (short)f2bf(v0[j]);
        o0[4 + j] = (short)f2bf(v1[j]);
        o1[j] = (short)f2bf(v2[j]);
        o1[4 + j] = (short)f2bf(v3[j]);
      }
      *reinterpret_cast<short8*>(&As[srow * BK + scol]) = o0;
      *reinterpret_cast<short8*>(&As[srow * BK + scol + 8]) = o1;
    }
    {
      const float* s = W + (size_t)(n0 + srow) * cH + k0 + scol;
      f32x4 v0 = *reinterpret_cast<const f32x4*>(s);
      f32x4 v1 = *reinterpret_cast<const f32x4*>(s + 4);
      f32x4 v2 = *reinterpret_cast<const f32x4*>(s + 8);
      f32x4 v3 = *reinterpret_cast<const f32x4*>(s + 12);
      short8 o0, o1;
#pragma unroll
      for (int j = 0; j < 4; ++j) {
        o0[j] = (short)f2bf(v0[j]);
        o0[4 + j] = (short)f2bf(v1[j]);
        o1[j] = (short)f2bf(v2[j]);
        o1[4 + j] = (short)f2bf(v3[j]);
      }
      *reinterpret_cast<short8*>(&Bs[srow * BK + scol]) = o0;
      *reinterpret_cast<short8*>(&Bs[srow * BK + scol + 8]) = o1;
    }
    __syncthreads();

    short8 af[4], bfr[4];
#pragma unroll
    for (int mi = 0; mi < 4; ++mi)
      af[mi] = *reinterpret_cast<const short8*>(
          &As[(wm * 64 + mi * 16 + lr) * BK + lg * 8]);
#pragma unroll
    for (int ni = 0; ni < 4; ++ni)
      bfr[ni] = *reinterpret_cast<const short8*>(
          &Bs[(wn * 64 + ni * 16 + lr) * BK + lg * 8]);
#pragma unroll
    for (int mi = 0; mi < 4; ++mi)
#pragma unroll
      for (int ni = 0; ni < 4; ++ni)
        acc[mi][ni] = __builtin_amdgcn_mfma_f32_16x16x32_bf16(
            af[mi], bfr[ni], acc[mi][ni], 0, 0, 0);
  }

#pragma unroll
  for (int ni = 0; ni < 4; ++ni) {
    const int col = n0 + wn * 64 + ni * 16 + lr;
    const float bvv = bias[col];
#pragma unroll
    for (int mi = 0; mi < 4; ++mi) {
      const int row = m0 + wm * 64 + mi * 16 + lg * 4;
#pragma unroll
      for (int r = 0; r < 4; ++r)
        Out[(size_t)(row + r) * cH + col] =
            f2bf((acc[mi][ni][r] + bvv) * oscale);
    }
  }
}

// ---------------- Flash attention ----------------
// Block = (qb, bh): 64 q-rows of one (b,h). 4 waves x 16 q-rows each.
// K/V tiles (64x64) staged once per block into double-buffered LDS (r7).
// r8 structure (best): row-sum via MFMA(pa, ones); transposed P pT[64][16]
// per wave (swizzled b64 writes + tr16 reads); 1 block barrier/iter;
// per-row max with 4 independent 4-deep shfl chains (ILP).
// r10: HW bf16 converts; Q pre-scaled so sc = z + mask (no 0.125 mul).
__global__ __launch_bounds__(256) void attn_kernel(
    const unsigned short* __restrict__ Qb,  // [B*S][H] bf16 (pre-scaled)
    const unsigned short* __restrict__ Kb,
    const unsigned short* __restrict__ Vb,
    const float* __restrict__ mask,         // [B][S]
    float* __restrict__ out) {              // [B*S][H] fp32
  __shared__ alignas(16) unsigned short Ks[2][64 * 64];    // 16 KB
  __shared__ alignas(16) unsigned short Vs[2][64 * 64];    // 16 KB
  __shared__ alignas(16) unsigned short plds[4][64 * 16];  // 8 KB, per-wave pT

  const int qb = blockIdx.x;  // 0..31
  const int bh = blockIdx.y;  // 0..31
  const int b = bh >> 4, h = bh & 15;
  const int t = threadIdx.x;
  const int w = t >> 6, l = t & 63, lr = l & 15, lg = l >> 4;
  const int q0 = qb * 64 + w * 16;

  const unsigned short* Kbase = Kb + (size_t)b * cS * cH + h * cHD;
  const unsigned short* Vbase = Vb + (size_t)b * cS * cH + h * cHD;
  const float* mbase = mask + b * cS;

  // Staging decode (r7-verified).
  int rK[2], cK[2], rV[2], cV[2];
#pragma unroll
  for (int s2 = 0; s2 < 2; ++s2) {
    const int g = (w * 2 + s2) * 64 + l;
    const int gr = g >> 3, gc = g & 7;
    rK[s2] = gr;
    cK[s2] = (gc ^ (gr & 7)) * 8;
    rV[s2] = (gr >> 2) * 4 + (gc >> 1);
    cV[s2] = (gr & 3) * 16 + (gc & 1) * 8;
  }

  const unsigned short* Qrow = Qb + (size_t)(b * cS + q0 + lr) * cH + h * cHD;
  short8 qf0 = *reinterpret_cast<const short8*>(Qrow + lg * 8);
  short8 qf1 = *reinterpret_cast<const short8*>(Qrow + 32 + lg * 8);

  // ones B-frag (bf16 1.0 = 0x3F80) for the row-sum MFMA
  short8 ones;
#pragma unroll
  for (int j = 0; j < 8; ++j) ones[j] = (short)0x3F80;

  f32x4 oacc[4];
#pragma unroll
  for (int d16 = 0; d16 < 4; ++d16) oacc[d16] = {0.f, 0.f, 0.f, 0.f};
  f32x4 osum = {0.f, 0.f, 0.f, 0.f};
  float mrow[4] = {-1e30f, -1e30f, -1e30f, -1e30f};

  auto stage = [&](int bufi, int kv0) {
#pragma unroll
    for (int s2 = 0; s2 < 2; ++s2) {
      gload_lds16(Kbase + (size_t)(kv0 + rK[s2]) * cH + cK[s2],
                  (char*)&Ks[bufi][0] + (w * 2 + s2) * 1024);
      gload_lds16(Vbase + (size_t)(kv0 + rV[s2]) * cH + cV[s2],
                  (char*)&Vs[bufi][0] + (w * 2 + s2) * 1024);
    }
  };

  stage(0, 0);
  asm volatile("s_waitcnt vmcnt(0)" ::: "memory");
  __syncthreads();

  unsigned short* pw = &plds[w][0];  // pT[64][16] (swizzled)

  constexpr int NT = cS / 64;  // 32
  for (int kt = 0; kt < NT; ++kt) {
    const int bufi = kt & 1;
    if (kt + 1 < NT) stage(bufi ^ 1, (kt + 1) * 64);

    const unsigned short* Kt = &Ks[bufi][0];
    const unsigned short* Vt = &Vs[bufi][0];
    const int kv0 = kt * 64;

    // ---- QK^T from swizzled K LDS (Q pre-scaled; sc = z + mask) ----
    f32x4 sc[4];
#pragma unroll
    for (int n = 0; n < 4; ++n) {
      const int kr = n * 16 + lr;
      const unsigned sw = (unsigned)((kr & 7) << 4);
      const unsigned b0 = ((unsigned)(kr * 128 + lg * 16)) ^ sw;
      const unsigned b1 = ((unsigned)(kr * 128 + 64 + lg * 16)) ^ sw;
      short8 kf0 = *reinterpret_cast<const short8*>((const char*)Kt + b0);
      short8 kf1 = *reinterpret_cast<const short8*>((const char*)Kt + b1);
      f32x4 z = {0.f, 0.f, 0.f, 0.f};
      z = __builtin_amdgcn_mfma_f32_16x16x32_bf16(qf0, kf0, z, 0, 0, 0);
      z = __builtin_amdgcn_mfma_f32_16x16x32_bf16(qf1, kf1, z, 0, 0, 0);
      const float mv = mbase[kv0 + kr];
      sc[n] = z + mv;
    }

    // ---- online softmax: per-row max (4 independent shfl chains, ILP);
    //      row-sum comes from MFMA ----
    float scalef[4];
    unsigned short pb[4][4];  // [n][r]
#pragma unroll
    for (int r = 0; r < 4; ++r) {
      float mx = fmaxf(fmaxf(sc[0][r], sc[1][r]), fmaxf(sc[2][r], sc[3][r]));
#pragma unroll
      for (int d = 1; d < 16; d <<= 1) mx = fmaxf(mx, __shfl_xor(mx, d));
      const float mnew = fmaxf(mrow[r], mx);
      scalef[r] = __expf(mrow[r] - mnew);
      mrow[r] = mnew;
#pragma unroll
      for (int n = 0; n < 4; ++n) pb[n][r] = f2bf(__expf(sc[n][r] - mnew));
    }
#pragma unroll
    for (int d16 = 0; d16 < 4; ++d16)
#pragma unroll
      for (int r = 0; r < 4; ++r) oacc[d16][r] *= scalef[r];
#pragma unroll
    for (int r = 0; r < 4; ++r) osum[r] *= scalef[r];

    // ---- P^T -> per-wave LDS [64][16], bank-swizzled ----
    const int pcb = (lg ^ (lr >> 2)) * 4;
#pragma unroll
    for (int n = 0; n < 4; ++n) {
      short4v v4 = {(short)pb[n][0], (short)pb[n][1], (short)pb[n][2],
                    (short)pb[n][3]};
      *reinterpret_cast<short4v*>(&pw[(n * 16 + lr) * 16 + pcb]) = v4;
    }
    asm volatile("s_waitcnt lgkmcnt(0)" ::: "memory");
    __builtin_amdgcn_sched_barrier(0);

    // ---- PV: A = P via tr16 on pT, B = V via tr16 (r7-verified) ----
#pragma unroll
    for (int ks2 = 0; ks2 < 2; ++ks2) {
      const int k0 = ks2 * 32 + lg * 8;
      const int key = (lg & 1) * 2;  // ((k0+j)>>2)&3 for j=0..3
      short4v t0 = tr16(&pw[(k0 + (lr >> 2)) * 16 + (((lr & 3) ^ key) * 4)]);
      short4v t1 =
          tr16(&pw[(k0 + 4 + (lr >> 2)) * 16 + (((lr & 3) ^ key ^ 1) * 4)]);
      short4v tv[8];
#pragma unroll
      for (int d16 = 0; d16 < 4; ++d16) {
        const unsigned short* a0 =
            Vt + (ks2 * 8 + lg * 2) * 256 + d16 * 64 + lr * 4;
        tv[2 * d16] = tr16(a0);            // V rows k0..+3, col lr
        tv[2 * d16 + 1] = tr16(a0 + 256);  // V rows k0+4..+7, col lr
      }
      asm volatile("s_waitcnt lgkmcnt(0)" ::: "memory");
      __builtin_amdgcn_sched_barrier(0);
      short8 pa;
#pragma unroll
      for (int j = 0; j < 4; ++j) {
        pa[j] = t0[j];
        pa[4 + j] = t1[j];
      }
      osum = __builtin_amdgcn_mfma_f32_16x16x32_bf16(pa, ones, osum, 0, 0, 0);
#pragma unroll
      for (int d16 = 0; d16 < 4; ++d16) {
        short8 vf;
#pragma unroll
        for (int j = 0; j < 4; ++j) {
          vf[j] = tv[2 * d16][j];
          vf[4 + j] = tv[2 * d16 + 1][j];
        }
        oacc[d16] =
            __builtin_amdgcn_mfma_f32_16x16x32_bf16(pa, vf, oacc[d16], 0, 0, 0);
      }
    }

    asm volatile("s_waitcnt vmcnt(0)" ::: "memory");
    __syncthreads();  // staged tile kt+1 ready; all waves done with buf kt
  }

  // fp32 store; denominator from the MFMA row-sum accumulator
  float* obase = out + (size_t)(b * cS + q0 + lg * 4) * cH + h * cHD;
#pragma unroll
  for (int r = 0; r < 4; ++r) {
    const float inv = 1.0f / osum[r];
#pragma unroll
    for (int d16 = 0; d16 < 4; ++d16)
      obase[(size_t)r * cH + d16 * 16 + lr] = oacc[d16][r] * inv;
  }
}

// ---------------- launcher ----------------
extern "C" void kernel_launch(void* const* d_in, const int* in_sizes, int n_in,
                              void* d_out, int out_size, void* d_ws,
                              size_t ws_size, hipStream_t stream) {
  const float* X = (const float*)d_in[0];     // [B,S,H]
  const float* mask = (const float*)d_in[1];  // [B,1,1,S]
  const float* Wq = (const float*)d_in[2];
  const float* bq = (const float*)d_in[3];
  const float* Wk = (const float*)d_in[4];
  const float* bk = (const float*)d_in[5];
  const float* Wv = (const float*)d_in[6];
  const float* bv = (const float*)d_in[7];
  float* outp = (float*)d_out;  // fp32 (reference output dtype)

  // workspace: Q,K,V bf16 -> 24 MB total
  char* ws = (char*)d_ws;
  const size_t MB = 1 << 20;
  unsigned short* Qb = (unsigned short*)(ws + 0 * MB);   // 8 MB
  unsigned short* Kb = (unsigned short*)(ws + 8 * MB);   // 8 MB
  unsigned short* Vb = (unsigned short*)(ws + 16 * MB);  // 8 MB

  qkv_gemm<<<dim3(24, 32), 256, 0, stream>>>(X, Wq, Wk, Wv, bq, bk, bv, Qb, Kb,
                                             Vb);
  attn_kernel<<<dim3(32, 32), 256, 0, stream>>>(Qb, Kb, Vb, mask, outp);
}

// Round 11
// 156.116 us; speedup vs baseline: 1.1312x; 1.0612x over previous
//
#include <hip/hip_runtime.h>
#include <hip/hip_bf16.h>
#include <stdint.h>

// Problem constants
constexpr int cB = 2;
constexpr int cS = 2048;
constexpr int cH = 1024;
constexpr int cNH = 16;
constexpr int cHD = 64;
constexpr int cBS = cB * cS;  // 4096

typedef short short8 __attribute__((ext_vector_type(8)));
typedef short short4v __attribute__((ext_vector_type(4)));
typedef float f32x4 __attribute__((ext_vector_type(4)));

// HW bf16 convert (RNE)
__device__ inline unsigned short f2bf(float f) {
  __hip_bfloat16 h = __float2bfloat16(f);
  return __builtin_bit_cast(unsigned short, h);
}

__device__ inline void gload_lds16(const void* g, void* l) {
  __builtin_amdgcn_global_load_lds(
      (const __attribute__((address_space(1))) void*)g,
      (__attribute__((address_space(3))) void*)l,
      16, 0, 0);
}

// ds_read_b64_tr_b16 (verified r7): each lane does a plain 64b read (4
// consecutive bf16) at its OWN addr; HW transposes within each 16-lane
// group: the group's reads form a 4x16 tile T (lane s supplies
// T[s>>2][(s&3)*4..+4)); lane a receives column a (elem j = T[j][a]).
__device__ inline short4v tr16(const unsigned short* p) {
  short4v d;
  auto p3 = (const __attribute__((address_space(3))) unsigned short*)p;
  asm volatile("ds_read_b64_tr_b16 %0, %1" : "=v"(d) : "v"(p3) : "memory");
  return d;
}

// ---------------- QKV GEMM (unchanged from r10, green) ----------------
constexpr int BM = 128, BN = 128, BK = 32;

__global__ __launch_bounds__(256) void qkv_gemm(
    const float* __restrict__ X,   // [4096][1024]
    const float* __restrict__ Wq,  // [1024][1024] (row=out, col=in)
    const float* __restrict__ Wk,
    const float* __restrict__ Wv,
    const float* __restrict__ bq, const float* __restrict__ bk,
    const float* __restrict__ bv,
    unsigned short* __restrict__ Qb, unsigned short* __restrict__ Kb,
    unsigned short* __restrict__ Vb) {
  __shared__ alignas(16) unsigned short As[BM * BK];  // [128][32]
  __shared__ alignas(16) unsigned short Bs[BN * BK];

  const int nb = blockIdx.x;  // 0..23
  const int mb = blockIdx.y;  // 0..31
  const int m0 = mb * BM;
  const int wsel = nb >> 3;
  const int n0 = (nb & 7) * BN;
  const float* W = (wsel == 0) ? Wq : (wsel == 1 ? Wk : Wv);
  const float* bias = (wsel == 0) ? bq : (wsel == 1 ? bk : bv);
  unsigned short* Out = (wsel == 0) ? Qb : (wsel == 1 ? Kb : Vb);
  const float oscale = (wsel == 0) ? 0.125f : 1.0f;  // fold 1/sqrt(HD) into Q

  const int t = threadIdx.x;
  const int w = t >> 6, l = t & 63, lr = l & 15, lg = l >> 4;
  const int wm = w >> 1, wn = w & 1;
  const int srow = t >> 1;
  const int scol = (t & 1) * 16;

  f32x4 acc[4][4];
#pragma unroll
  for (int mi = 0; mi < 4; ++mi)
#pragma unroll
    for (int ni = 0; ni < 4; ++ni) acc[mi][ni] = {0.f, 0.f, 0.f, 0.f};

  for (int kt = 0; kt < cH / BK; ++kt) {
    const int k0 = kt * BK;
    __syncthreads();
    {
      const float* s = X + (size_t)(m0 + srow) * cH + k0 + scol;
      f32x4 v0 = *reinterpret_cast<const f32x4*>(s);
      f32x4 v1 = *reinterpret_cast<const f32x4*>(s + 4);
      f32x4 v2 = *reinterpret_cast<const f32x4*>(s + 8);
      f32x4 v3 = *reinterpret_cast<const f32x4*>(s + 12);
      short8 o0, o1;
#pragma unroll
      for (int j = 0; j < 4; ++j) {
        o0[j] = (short)f2bf(v0[j]);
        o0[4 + j] = (short)f2bf(v1[j]);
        o1[j] = (short)f2bf(v2[j]);
        o1[4 + j] = (short)f2bf(v3[j]);
      }
      *reinterpret_cast<short8*>(&As[srow * BK + scol]) = o0;
      *reinterpret_cast<short8*>(&As[srow * BK + scol + 8]) = o1;
    }
    {
      const float* s = W + (size_t)(n0 + srow) * cH + k0 + scol;
      f32x4 v0 = *reinterpret_cast<const f32x4*>(s);
      f32x4 v1 = *reinterpret_cast<const f32x4*>(s + 4);
      f32x4 v2 = *reinterpret_cast<const f32x4*>(s + 8);
      f32x4 v3 = *reinterpret_cast<const f32x4*>(s + 12);
      short8 o0, o1;
#pragma unroll
      for (int j = 0; j < 4; ++j) {
        o0[j] = (short)f2bf(v0[j]);
        o0[4 + j] = (short)f2bf(v1[j]);
        o1[j] = (short)f2bf(v2[j]);
        o1[4 + j] = (short)f2bf(v3[j]);
      }
      *reinterpret_cast<short8*>(&Bs[srow * BK + scol]) = o0;
      *reinterpret_cast<short8*>(&Bs[srow * BK + scol + 8]) = o1;
    }
    __syncthreads();

    short8 af[4], bfr[4];
#pragma unroll
    for (int mi = 0; mi < 4; ++mi)
      af[mi] = *reinterpret_cast<const short8*>(
          &As[(wm * 64 + mi * 16 + lr) * BK + lg * 8]);
#pragma unroll
    for (int ni = 0; ni < 4; ++ni)
      bfr[ni] = *reinterpret_cast<const short8*>(
          &Bs[(wn * 64 + ni * 16 + lr) * BK + lg * 8]);
#pragma unroll
    for (int mi = 0; mi < 4; ++mi)
#pragma unroll
      for (int ni = 0; ni < 4; ++ni)
        acc[mi][ni] = __builtin_amdgcn_mfma_f32_16x16x32_bf16(
            af[mi], bfr[ni], acc[mi][ni], 0, 0, 0);
  }

#pragma unroll
  for (int ni = 0; ni < 4; ++ni) {
    const int col = n0 + wn * 64 + ni * 16 + lr;
    const float bvv = bias[col];
#pragma unroll
    for (int mi = 0; mi < 4; ++mi) {
      const int row = m0 + wm * 64 + mi * 16 + lg * 4;
#pragma unroll
      for (int r = 0; r < 4; ++r)
        Out[(size_t)(row + r) * cH + col] =
            f2bf((acc[mi][ni][r] + bvv) * oscale);
    }
  }
}

// ---------------- Flash attention ----------------
// r11: block = (qb, bh) covering 128 q-rows; 4 waves x 32 q-rows each
// (2 subtiles of 16, duplicating the r8-verified per-subtile machinery).
// K/V tiles (64x64) staged once per block (shared by all 8 q-subtiles);
// V tr16 fragments read once per ks2, reused by both subtiles.
__global__ __launch_bounds__(256) void attn_kernel(
    const unsigned short* __restrict__ Qb,  // [B*S][H] bf16 (pre-scaled)
    const unsigned short* __restrict__ Kb,
    const unsigned short* __restrict__ Vb,
    const float* __restrict__ mask,         // [B][S]
    float* __restrict__ out) {              // [B*S][H] fp32
  __shared__ alignas(16) unsigned short Ks[2][64 * 64];       // 16 KB
  __shared__ alignas(16) unsigned short Vs[2][64 * 64];       // 16 KB
  __shared__ alignas(16) unsigned short plds[4][2][64 * 16];  // 16 KB

  const int qb = blockIdx.x;  // 0..15
  const int bh = blockIdx.y;  // 0..31
  const int b = bh >> 4, h = bh & 15;
  const int t = threadIdx.x;
  const int w = t >> 6, l = t & 63, lr = l & 15, lg = l >> 4;
  const int q0 = qb * 128 + w * 32;

  const unsigned short* Kbase = Kb + (size_t)b * cS * cH + h * cHD;
  const unsigned short* Vbase = Vb + (size_t)b * cS * cH + h * cHD;
  const float* mbase = mask + b * cS;

  // Staging decode (r7-verified).
  int rK[2], cK[2], rV[2], cV[2];
#pragma unroll
  for (int s2 = 0; s2 < 2; ++s2) {
    const int g = (w * 2 + s2) * 64 + l;
    const int gr = g >> 3, gc = g & 7;
    rK[s2] = gr;
    cK[s2] = (gc ^ (gr & 7)) * 8;
    rV[s2] = (gr >> 2) * 4 + (gc >> 1);
    cV[s2] = (gr & 3) * 16 + (gc & 1) * 8;
  }

  // Q fragments for 2 subtiles
  short8 qf[2][2];
#pragma unroll
  for (int qi = 0; qi < 2; ++qi) {
    const unsigned short* Qrow =
        Qb + (size_t)(b * cS + q0 + qi * 16 + lr) * cH + h * cHD;
    qf[qi][0] = *reinterpret_cast<const short8*>(Qrow + lg * 8);
    qf[qi][1] = *reinterpret_cast<const short8*>(Qrow + 32 + lg * 8);
  }

  short8 ones;
#pragma unroll
  for (int j = 0; j < 8; ++j) ones[j] = (short)0x3F80;

  f32x4 oacc[2][4];
  f32x4 osum[2];
  float mrow[2][4];
#pragma unroll
  for (int qi = 0; qi < 2; ++qi) {
    osum[qi] = {0.f, 0.f, 0.f, 0.f};
#pragma unroll
    for (int d16 = 0; d16 < 4; ++d16) oacc[qi][d16] = {0.f, 0.f, 0.f, 0.f};
#pragma unroll
    for (int r = 0; r < 4; ++r) mrow[qi][r] = -1e30f;
  }

  auto stage = [&](int bufi, int kv0) {
#pragma unroll
    for (int s2 = 0; s2 < 2; ++s2) {
      gload_lds16(Kbase + (size_t)(kv0 + rK[s2]) * cH + cK[s2],
                  (char*)&Ks[bufi][0] + (w * 2 + s2) * 1024);
      gload_lds16(Vbase + (size_t)(kv0 + rV[s2]) * cH + cV[s2],
                  (char*)&Vs[bufi][0] + (w * 2 + s2) * 1024);
    }
  };

  stage(0, 0);
  asm volatile("s_waitcnt vmcnt(0)" ::: "memory");
  __syncthreads();

  unsigned short* pw0 = &plds[w][0][0];
  unsigned short* pw1 = &plds[w][1][0];

  constexpr int NT = cS / 64;  // 32
  for (int kt = 0; kt < NT; ++kt) {
    const int bufi = kt & 1;
    if (kt + 1 < NT) stage(bufi ^ 1, (kt + 1) * 64);

    const unsigned short* Kt = &Ks[bufi][0];
    const unsigned short* Vt = &Vs[bufi][0];
    const int kv0 = kt * 64;

    // mask values (k-indexed; shared by both subtiles)
    float mv[4];
#pragma unroll
    for (int n = 0; n < 4; ++n) mv[n] = mbase[kv0 + n * 16 + lr];

    // ---- QK^T for both subtiles ----
    f32x4 sc[2][4];
#pragma unroll
    for (int n = 0; n < 4; ++n) {
      const int kr = n * 16 + lr;
      const unsigned sw = (unsigned)((kr & 7) << 4);
      const unsigned b0 = ((unsigned)(kr * 128 + lg * 16)) ^ sw;
      const unsigned b1 = ((unsigned)(kr * 128 + 64 + lg * 16)) ^ sw;
      short8 kf0 = *reinterpret_cast<const short8*>((const char*)Kt + b0);
      short8 kf1 = *reinterpret_cast<const short8*>((const char*)Kt + b1);
#pragma unroll
      for (int qi = 0; qi < 2; ++qi) {
        f32x4 z = {0.f, 0.f, 0.f, 0.f};
        z = __builtin_amdgcn_mfma_f32_16x16x32_bf16(qf[qi][0], kf0, z, 0, 0, 0);
        z = __builtin_amdgcn_mfma_f32_16x16x32_bf16(qf[qi][1], kf1, z, 0, 0, 0);
        sc[qi][n] = z + mv[n];
      }
    }

    // ---- online softmax per subtile (8 independent shfl chains total) ----
#pragma unroll
    for (int qi = 0; qi < 2; ++qi) {
      float scalef[4];
      unsigned short pb[4][4];  // [n][r]
#pragma unroll
      for (int r = 0; r < 4; ++r) {
        float mx = fmaxf(fmaxf(sc[qi][0][r], sc[qi][1][r]),
                         fmaxf(sc[qi][2][r], sc[qi][3][r]));
#pragma unroll
        for (int d = 1; d < 16; d <<= 1) mx = fmaxf(mx, __shfl_xor(mx, d));
        const float mnew = fmaxf(mrow[qi][r], mx);
        scalef[r] = __expf(mrow[qi][r] - mnew);
        mrow[qi][r] = mnew;
#pragma unroll
        for (int n = 0; n < 4; ++n) pb[n][r] = f2bf(__expf(sc[qi][n][r] - mnew));
      }
#pragma unroll
      for (int d16 = 0; d16 < 4; ++d16)
#pragma unroll
        for (int r = 0; r < 4; ++r) oacc[qi][d16][r] *= scalef[r];
#pragma unroll
      for (int r = 0; r < 4; ++r) osum[qi][r] *= scalef[r];

      // P^T -> per-(wave,qi) LDS [64][16], bank-swizzled (r8 layout)
      unsigned short* pw = qi ? pw1 : pw0;
      const int pcb = (lg ^ (lr >> 2)) * 4;
#pragma unroll
      for (int n = 0; n < 4; ++n) {
        short4v v4 = {(short)pb[n][0], (short)pb[n][1], (short)pb[n][2],
                      (short)pb[n][3]};
        *reinterpret_cast<short4v*>(&pw[(n * 16 + lr) * 16 + pcb]) = v4;
      }
    }
    asm volatile("s_waitcnt lgkmcnt(0)" ::: "memory");
    __builtin_amdgcn_sched_barrier(0);

    // ---- PV: V fragments read once per ks2, used by both subtiles ----
#pragma unroll
    for (int ks2 = 0; ks2 < 2; ++ks2) {
      const int k0 = ks2 * 32 + lg * 8;
      const int key = (lg & 1) * 2;
      short4v t0a = tr16(&pw0[(k0 + (lr >> 2)) * 16 + (((lr & 3) ^ key) * 4)]);
      short4v t1a =
          tr16(&pw0[(k0 + 4 + (lr >> 2)) * 16 + (((lr & 3) ^ key ^ 1) * 4)]);
      short4v t0b = tr16(&pw1[(k0 + (lr >> 2)) * 16 + (((lr & 3) ^ key) * 4)]);
      short4v t1b =
          tr16(&pw1[(k0 + 4 + (lr >> 2)) * 16 + (((lr & 3) ^ key ^ 1) * 4)]);
      short4v tv[8];
#pragma unroll
      for (int d16 = 0; d16 < 4; ++d16) {
        const unsigned short* a0 =
            Vt + (ks2 * 8 + lg * 2) * 256 + d16 * 64 + lr * 4;
        tv[2 * d16] = tr16(a0);            // V rows k0..+3, col lr
        tv[2 * d16 + 1] = tr16(a0 + 256);  // V rows k0+4..+7, col lr
      }
      asm volatile("s_waitcnt lgkmcnt(0)" ::: "memory");
      __builtin_amdgcn_sched_barrier(0);
      short8 paA, paB;
#pragma unroll
      for (int j = 0; j < 4; ++j) {
        paA[j] = t0a[j];
        paA[4 + j] = t1a[j];
        paB[j] = t0b[j];
        paB[4 + j] = t1b[j];
      }
      osum[0] = __builtin_amdgcn_mfma_f32_16x16x32_bf16(paA, ones, osum[0], 0, 0, 0);
      osum[1] = __builtin_amdgcn_mfma_f32_16x16x32_bf16(paB, ones, osum[1], 0, 0, 0);
#pragma unroll
      for (int d16 = 0; d16 < 4; ++d16) {
        short8 vf;
#pragma unroll
        for (int j = 0; j < 4; ++j) {
          vf[j] = tv[2 * d16][j];
          vf[4 + j] = tv[2 * d16 + 1][j];
        }
        oacc[0][d16] =
            __builtin_amdgcn_mfma_f32_16x16x32_bf16(paA, vf, oacc[0][d16], 0, 0, 0);
        oacc[1][d16] =
            __builtin_amdgcn_mfma_f32_16x16x32_bf16(paB, vf, oacc[1][d16], 0, 0, 0);
      }
    }

    asm volatile("s_waitcnt vmcnt(0)" ::: "memory");
    __syncthreads();  // staged tile kt+1 ready; all waves done with buf kt
  }

  // fp32 store; denominator from the MFMA row-sum accumulator
#pragma unroll
  for (int qi = 0; qi < 2; ++qi) {
    float* obase =
        out + (size_t)(b * cS + q0 + qi * 16 + lg * 4) * cH + h * cHD;
#pragma unroll
    for (int r = 0; r < 4; ++r) {
      const float inv = 1.0f / osum[qi][r];
#pragma unroll
      for (int d16 = 0; d16 < 4; ++d16)
        obase[(size_t)r * cH + d16 * 16 + lr] = oacc[qi][d16][r] * inv;
    }
  }
}

// ---------------- launcher ----------------
extern "C" void kernel_launch(void* const* d_in, const int* in_sizes, int n_in,
                              void* d_out, int out_size, void* d_ws,
                              size_t ws_size, hipStream_t stream) {
  const float* X = (const float*)d_in[0];     // [B,S,H]
  const float* mask = (const float*)d_in[1];  // [B,1,1,S]
  const float* Wq = (const float*)d_in[2];
  const float* bq = (const float*)d_in[3];
  const float* Wk = (const float*)d_in[4];
  const float* bk = (const float*)d_in[5];
  const float* Wv = (const float*)d_in[6];
  const float* bv = (const float*)d_in[7];
  float* outp = (float*)d_out;  // fp32 (reference output dtype)

  // workspace: Q,K,V bf16 -> 24 MB total
  char* ws = (char*)d_ws;
  const size_t MB = 1 << 20;
  unsigned short* Qb = (unsigned short*)(ws + 0 * MB);   // 8 MB
  unsigned short* Kb = (unsigned short*)(ws + 8 * MB);   // 8 MB
  unsigned short* Vb = (unsigned short*)(ws + 16 * MB);  // 8 MB

  qkv_gemm<<<dim3(24, 32), 256, 0, stream>>>(X, Wq, Wk, Wv, bq, bk, bv, Qb, Kb,
                                             Vb);
  attn_kernel<<<dim3(16, 32), 256, 0, stream>>>(Qb, Kb, Vb, mask, outp);
}

// Round 13
// 147.350 us; speedup vs baseline: 1.1985x; 1.0595x over previous
//
#include <hip/hip_runtime.h>
#include <hip/hip_bf16.h>
#include <stdint.h>

// Problem constants
constexpr int cB = 2;
constexpr int cS = 2048;
constexpr int cH = 1024;
constexpr int cNH = 16;
constexpr int cHD = 64;
constexpr int cBS = cB * cS;  // 4096

typedef short short8 __attribute__((ext_vector_type(8)));
typedef short short4v __attribute__((ext_vector_type(4)));
typedef float f32x4 __attribute__((ext_vector_type(4)));

// HW bf16 convert (RNE)
__device__ inline unsigned short f2bf(float f) {
  __hip_bfloat16 h = __float2bfloat16(f);
  return __builtin_bit_cast(unsigned short, h);
}

__device__ inline void gload_lds16(const void* g, void* l) {
  __builtin_amdgcn_global_load_lds(
      (const __attribute__((address_space(1))) void*)g,
      (__attribute__((address_space(3))) void*)l,
      16, 0, 0);
}

// ds_read_b64_tr_b16 (verified r7): each lane does a plain 64b read (4
// consecutive bf16) at its OWN addr; HW transposes within each 16-lane
// group: the group's reads form a 4x16 tile T (lane s supplies
// T[s>>2][(s&3)*4..+4)); lane a receives column a (elem j = T[j][a]).
__device__ inline short4v tr16(const unsigned short* p) {
  short4v d;
  auto p3 = (const __attribute__((address_space(3))) unsigned short*)p;
  asm volatile("ds_read_b64_tr_b16 %0, %1" : "=v"(d) : "v"(p3) : "memory");
  return d;
}

// One DPP max step: x = max(x, row_ror<CTRL>(x)). CTRL must be a literal
// (builtin requires constant integer -> template parameter).
template <int CTRL>
__device__ inline float dppmax(float x) {
  int v = __builtin_bit_cast(int, x);
  int y = __builtin_amdgcn_update_dpp(0, v, CTRL, 0xf, 0xf, true);
  return fmaxf(x, __builtin_bit_cast(float, y));
}

// 16-lane max reduction on the VALU (DPP row rotates; no DS-pipe traffic).
// row_ror:N ctrl = 0x120+N; ror 1,2,4,8 -> every lane holds the 16-row max.
__device__ inline float rowmax16(float x) {
  x = dppmax<0x121>(x);
  x = dppmax<0x122>(x);
  x = dppmax<0x124>(x);
  x = dppmax<0x128>(x);
  return x;
}

// ---------------- QKV GEMM (unchanged from r10, green) ----------------
constexpr int BM = 128, BN = 128, BK = 32;

__global__ __launch_bounds__(256) void qkv_gemm(
    const float* __restrict__ X,   // [4096][1024]
    const float* __restrict__ Wq,  // [1024][1024] (row=out, col=in)
    const float* __restrict__ Wk,
    const float* __restrict__ Wv,
    const float* __restrict__ bq, const float* __restrict__ bk,
    const float* __restrict__ bv,
    unsigned short* __restrict__ Qb, unsigned short* __restrict__ Kb,
    unsigned short* __restrict__ Vb) {
  __shared__ alignas(16) unsigned short As[BM * BK];  // [128][32]
  __shared__ alignas(16) unsigned short Bs[BN * BK];

  const int nb = blockIdx.x;  // 0..23
  const int mb = blockIdx.y;  // 0..31
  const int m0 = mb * BM;
  const int wsel = nb >> 3;
  const int n0 = (nb & 7) * BN;
  const float* W = (wsel == 0) ? Wq : (wsel == 1 ? Wk : Wv);
  const float* bias = (wsel == 0) ? bq : (wsel == 1 ? bk : bv);
  unsigned short* Out = (wsel == 0) ? Qb : (wsel == 1 ? Kb : Vb);
  const float oscale = (wsel == 0) ? 0.125f : 1.0f;  // fold 1/sqrt(HD) into Q

  const int t = threadIdx.x;
  const int w = t >> 6, l = t & 63, lr = l & 15, lg = l >> 4;
  const int wm = w >> 1, wn = w & 1;
  const int srow = t >> 1;
  const int scol = (t & 1) * 16;

  f32x4 acc[4][4];
#pragma unroll
  for (int mi = 0; mi < 4; ++mi)
#pragma unroll
    for (int ni = 0; ni < 4; ++ni) acc[mi][ni] = {0.f, 0.f, 0.f, 0.f};

  for (int kt = 0; kt < cH / BK; ++kt) {
    const int k0 = kt * BK;
    __syncthreads();
    {
      const float* s = X + (size_t)(m0 + srow) * cH + k0 + scol;
      f32x4 v0 = *reinterpret_cast<const f32x4*>(s);
      f32x4 v1 = *reinterpret_cast<const f32x4*>(s + 4);
      f32x4 v2 = *reinterpret_cast<const f32x4*>(s + 8);
      f32x4 v3 = *reinterpret_cast<const f32x4*>(s + 12);
      short8 o0, o1;
#pragma unroll
      for (int j = 0; j < 4; ++j) {
        o0[j] = (short)f2bf(v0[j]);
        o0[4 + j] = (short)f2bf(v1[j]);
        o1[j] = (short)f2bf(v2[j]);
        o1[4 + j] = (short)f2bf(v3[j]);
      }
      *reinterpret_cast<short8*>(&As[srow * BK + scol]) = o0;
      *reinterpret_cast<short8*>(&As[srow * BK + scol + 8]) = o1;
    }
    {
      const float* s = W + (size_t)(n0 + srow) * cH + k0 + scol;
      f32x4 v0 = *reinterpret_cast<const f32x4*>(s);
      f32x4 v1 = *reinterpret_cast<const f32x4*>(s + 4);
      f32x4 v2 = *reinterpret_cast<const f32x4*>(s + 8);
      f32x4 v3 = *reinterpret_cast<const f32x4*>(s + 12);
      short8 o0, o1;
#pragma unroll
      for (int j = 0; j < 4; ++j) {
        o0[j] = (short)f2bf(v0[j]);
        o0[4 + j] = (short)f2bf(v1[j]);
        o1[j] = (short)f2bf(v2[j]);
        o1[4 + j] = (short)f2bf(v3[j]);
      }
      *reinterpret_cast<short8*>(&Bs[srow * BK + scol]) = o0;
      *reinterpret_cast<short8*>(&Bs[srow * BK + scol + 8]) = o1;
    }
    __syncthreads();

    short8 af[4], bfr[4];
#pragma unroll
    for (int mi = 0; mi < 4; ++mi)
      af[mi] = *reinterpret_cast<const short8*>(
          &As[(wm * 64 + mi * 16 + lr) * BK + lg * 8]);
#pragma unroll
    for (int ni = 0; ni < 4; ++ni)
      bfr[ni] = *reinterpret_cast<const short8*>(
          &Bs[(wn * 64 + ni * 16 + lr) * BK + lg * 8]);
#pragma unroll
    for (int mi = 0; mi < 4; ++mi)
#pragma unroll
      for (int ni = 0; ni < 4; ++ni)
        acc[mi][ni] = __builtin_amdgcn_mfma_f32_16x16x32_bf16(
            af[mi], bfr[ni], acc[mi][ni], 0, 0, 0);
  }

#pragma unroll
  for (int ni = 0; ni < 4; ++ni) {
    const int col = n0 + wn * 64 + ni * 16 + lr;
    const float bvv = bias[col];
#pragma unroll
    for (int mi = 0; mi < 4; ++mi) {
      const int row = m0 + wm * 64 + mi * 16 + lg * 4;
#pragma unroll
      for (int r = 0; r < 4; ++r)
        Out[(size_t)(row + r) * cH + col] =
            f2bf((acc[mi][ni][r] + bvv) * oscale);
    }
  }
}

// ---------------- Flash attention ----------------
// r11 structure: block = (qb, bh) covering 128 q-rows; 4 waves x 32 q-rows
// (2 subtiles of 16). K/V staged once per block; V tr16 frags shared.
// r13 (=r12 intent): softmax max-reduce via DPP row_ror on the VALU (was
// __shfl_xor = ds_swizzle on the saturated DS pipe; -32 DS ops/wave/iter).
__global__ __launch_bounds__(256) void attn_kernel(
    const unsigned short* __restrict__ Qb,  // [B*S][H] bf16 (pre-scaled)
    const unsigned short* __restrict__ Kb,
    const unsigned short* __restrict__ Vb,
    const float* __restrict__ mask,         // [B][S]
    float* __restrict__ out) {              // [B*S][H] fp32
  __shared__ alignas(16) unsigned short Ks[2][64 * 64];       // 16 KB
  __shared__ alignas(16) unsigned short Vs[2][64 * 64];       // 16 KB
  __shared__ alignas(16) unsigned short plds[4][2][64 * 16];  // 16 KB

  const int qb = blockIdx.x;  // 0..15
  const int bh = blockIdx.y;  // 0..31
  const int b = bh >> 4, h = bh & 15;
  const int t = threadIdx.x;
  const int w = t >> 6, l = t & 63, lr = l & 15, lg = l >> 4;
  const int q0 = qb * 128 + w * 32;

  const unsigned short* Kbase = Kb + (size_t)b * cS * cH + h * cHD;
  const unsigned short* Vbase = Vb + (size_t)b * cS * cH + h * cHD;
  const float* mbase = mask + b * cS;

  // Staging decode (r7-verified).
  int rK[2], cK[2], rV[2], cV[2];
#pragma unroll
  for (int s2 = 0; s2 < 2; ++s2) {
    const int g = (w * 2 + s2) * 64 + l;
    const int gr = g >> 3, gc = g & 7;
    rK[s2] = gr;
    cK[s2] = (gc ^ (gr & 7)) * 8;
    rV[s2] = (gr >> 2) * 4 + (gc >> 1);
    cV[s2] = (gr & 3) * 16 + (gc & 1) * 8;
  }

  // Q fragments for 2 subtiles
  short8 qf[2][2];
#pragma unroll
  for (int qi = 0; qi < 2; ++qi) {
    const unsigned short* Qrow =
        Qb + (size_t)(b * cS + q0 + qi * 16 + lr) * cH + h * cHD;
    qf[qi][0] = *reinterpret_cast<const short8*>(Qrow + lg * 8);
    qf[qi][1] = *reinterpret_cast<const short8*>(Qrow + 32 + lg * 8);
  }

  short8 ones;
#pragma unroll
  for (int j = 0; j < 8; ++j) ones[j] = (short)0x3F80;

  f32x4 oacc[2][4];
  f32x4 osum[2];
  float mrow[2][4];
#pragma unroll
  for (int qi = 0; qi < 2; ++qi) {
    osum[qi] = {0.f, 0.f, 0.f, 0.f};
#pragma unroll
    for (int d16 = 0; d16 < 4; ++d16) oacc[qi][d16] = {0.f, 0.f, 0.f, 0.f};
#pragma unroll
    for (int r = 0; r < 4; ++r) mrow[qi][r] = -1e30f;
  }

  auto stage = [&](int bufi, int kv0) {
#pragma unroll
    for (int s2 = 0; s2 < 2; ++s2) {
      gload_lds16(Kbase + (size_t)(kv0 + rK[s2]) * cH + cK[s2],
                  (char*)&Ks[bufi][0] + (w * 2 + s2) * 1024);
      gload_lds16(Vbase + (size_t)(kv0 + rV[s2]) * cH + cV[s2],
                  (char*)&Vs[bufi][0] + (w * 2 + s2) * 1024);
    }
  };

  stage(0, 0);
  asm volatile("s_waitcnt vmcnt(0)" ::: "memory");
  __syncthreads();

  unsigned short* pw0 = &plds[w][0][0];
  unsigned short* pw1 = &plds[w][1][0];

  constexpr int NT = cS / 64;  // 32
  for (int kt = 0; kt < NT; ++kt) {
    const int bufi = kt & 1;
    if (kt + 1 < NT) stage(bufi ^ 1, (kt + 1) * 64);

    const unsigned short* Kt = &Ks[bufi][0];
    const unsigned short* Vt = &Vs[bufi][0];
    const int kv0 = kt * 64;

    // mask values (k-indexed; shared by both subtiles)
    float mv[4];
#pragma unroll
    for (int n = 0; n < 4; ++n) mv[n] = mbase[kv0 + n * 16 + lr];

    // ---- QK^T for both subtiles ----
    f32x4 sc[2][4];
#pragma unroll
    for (int n = 0; n < 4; ++n) {
      const int kr = n * 16 + lr;
      const unsigned sw = (unsigned)((kr & 7) << 4);
      const unsigned b0 = ((unsigned)(kr * 128 + lg * 16)) ^ sw;
      const unsigned b1 = ((unsigned)(kr * 128 + 64 + lg * 16)) ^ sw;
      short8 kf0 = *reinterpret_cast<const short8*>((const char*)Kt + b0);
      short8 kf1 = *reinterpret_cast<const short8*>((const char*)Kt + b1);
#pragma unroll
      for (int qi = 0; qi < 2; ++qi) {
        f32x4 z = {0.f, 0.f, 0.f, 0.f};
        z = __builtin_amdgcn_mfma_f32_16x16x32_bf16(qf[qi][0], kf0, z, 0, 0, 0);
        z = __builtin_amdgcn_mfma_f32_16x16x32_bf16(qf[qi][1], kf1, z, 0, 0, 0);
        sc[qi][n] = z + mv[n];
      }
    }

    // ---- online softmax per subtile (max via DPP on VALU; sum via MFMA) ----
#pragma unroll
    for (int qi = 0; qi < 2; ++qi) {
      float scalef[4];
      unsigned short pb[4][4];  // [n][r]
#pragma unroll
      for (int r = 0; r < 4; ++r) {
        float mx = fmaxf(fmaxf(sc[qi][0][r], sc[qi][1][r]),
                         fmaxf(sc[qi][2][r], sc[qi][3][r]));
        mx = rowmax16(mx);
        const float mnew = fmaxf(mrow[qi][r], mx);
        scalef[r] = __expf(mrow[qi][r] - mnew);
        mrow[qi][r] = mnew;
#pragma unroll
        for (int n = 0; n < 4; ++n) pb[n][r] = f2bf(__expf(sc[qi][n][r] - mnew));
      }
#pragma unroll
      for (int d16 = 0; d16 < 4; ++d16)
#pragma unroll
        for (int r = 0; r < 4; ++r) oacc[qi][d16][r] *= scalef[r];
#pragma unroll
      for (int r = 0; r < 4; ++r) osum[qi][r] *= scalef[r];

      // P^T -> per-(wave,qi) LDS [64][16], bank-swizzled (r8 layout)
      unsigned short* pw = qi ? pw1 : pw0;
      const int pcb = (lg ^ (lr >> 2)) * 4;
#pragma unroll
      for (int n = 0; n < 4; ++n) {
        short4v v4 = {(short)pb[n][0], (short)pb[n][1], (short)pb[n][2],
                      (short)pb[n][3]};
        *reinterpret_cast<short4v*>(&pw[(n * 16 + lr) * 16 + pcb]) = v4;
      }
    }
    asm volatile("s_waitcnt lgkmcnt(0)" ::: "memory");
    __builtin_amdgcn_sched_barrier(0);

    // ---- PV: V fragments read once per ks2, used by both subtiles ----
#pragma unroll
    for (int ks2 = 0; ks2 < 2; ++ks2) {
      const int k0 = ks2 * 32 + lg * 8;
      const int key = (lg & 1) * 2;
      short4v t0a = tr16(&pw0[(k0 + (lr >> 2)) * 16 + (((lr & 3) ^ key) * 4)]);
      short4v t1a =
          tr16(&pw0[(k0 + 4 + (lr >> 2)) * 16 + (((lr & 3) ^ key ^ 1) * 4)]);
      short4v t0b = tr16(&pw1[(k0 + (lr >> 2)) * 16 + (((lr & 3) ^ key) * 4)]);
      short4v t1b =
          tr16(&pw1[(k0 + 4 + (lr >> 2)) * 16 + (((lr & 3) ^ key ^ 1) * 4)]);
      short4v tv[8];
#pragma unroll
      for (int d16 = 0; d16 < 4; ++d16) {
        const unsigned short* a0 =
            Vt + (ks2 * 8 + lg * 2) * 256 + d16 * 64 + lr * 4;
        tv[2 * d16] = tr16(a0);            // V rows k0..+3, col lr
        tv[2 * d16 + 1] = tr16(a0 + 256);  // V rows k0+4..+7, col lr
      }
      asm volatile("s_waitcnt lgkmcnt(0)" ::: "memory");
      __builtin_amdgcn_sched_barrier(0);
      short8 paA, paB;
#pragma unroll
      for (int j = 0; j < 4; ++j) {
        paA[j] = t0a[j];
        paA[4 + j] = t1a[j];
        paB[j] = t0b[j];
        paB[4 + j] = t1b[j];
      }
      osum[0] = __builtin_amdgcn_mfma_f32_16x16x32_bf16(paA, ones, osum[0], 0, 0, 0);
      osum[1] = __builtin_amdgcn_mfma_f32_16x16x32_bf16(paB, ones, osum[1], 0, 0, 0);
#pragma unroll
      for (int d16 = 0; d16 < 4; ++d16) {
        short8 vf;
#pragma unroll
        for (int j = 0; j < 4; ++j) {
          vf[j] = tv[2 * d16][j];
          vf[4 + j] = tv[2 * d16 + 1][j];
        }
        oacc[0][d16] =
            __builtin_amdgcn_mfma_f32_16x16x32_bf16(paA, vf, oacc[0][d16], 0, 0, 0);
        oacc[1][d16] =
            __builtin_amdgcn_mfma_f32_16x16x32_bf16(paB, vf, oacc[1][d16], 0, 0, 0);
      }
    }

    asm volatile("s_waitcnt vmcnt(0)" ::: "memory");
    __syncthreads();  // staged tile kt+1 ready; all waves done with buf kt
  }

  // fp32 store; denominator from the MFMA row-sum accumulator
#pragma unroll
  for (int qi = 0; qi < 2; ++qi) {
    float* obase =
        out + (size_t)(b * cS + q0 + qi * 16 + lg * 4) * cH + h * cHD;
#pragma unroll
    for (int r = 0; r < 4; ++r) {
      const float inv = 1.0f / osum[qi][r];
#pragma unroll
      for (int d16 = 0; d16 < 4; ++d16)
        obase[(size_t)r * cH + d16 * 16 + lr] = oacc[qi][d16][r] * inv;
    }
  }
}

// ---------------- launcher ----------------
extern "C" void kernel_launch(void* const* d_in, const int* in_sizes, int n_in,
                              void* d_out, int out_size, void* d_ws,
                              size_t ws_size, hipStream_t stream) {
  const float* X = (const float*)d_in[0];     // [B,S,H]
  const float* mask = (const float*)d_in[1];  // [B,1,1,S]
  const float* Wq = (const float*)d_in[2];
  const float* bq = (const float*)d_in[3];
  const float* Wk = (const float*)d_in[4];
  const float* bk = (const float*)d_in[5];
  const float* Wv = (const float*)d_in[6];
  const float* bv = (const float*)d_in[7];
  float* outp = (float*)d_out;  // fp32 (reference output dtype)

  // workspace: Q,K,V bf16 -> 24 MB total
  char* ws = (char*)d_ws;
  const size_t MB = 1 << 20;
  unsigned short* Qb = (unsigned short*)(ws + 0 * MB);   // 8 MB
  unsigned short* Kb = (unsigned short*)(ws + 8 * MB);   // 8 MB
  unsigned short* Vb = (unsigned short*)(ws + 16 * MB);  // 8 MB

  qkv_gemm<<<dim3(24, 32), 256, 0, stream>>>(X, Wq, Wk, Wv, bq, bk, bv, Qb, Kb,
                                             Vb);
  attn_kernel<<<dim3(16, 32), 256, 0, stream>>>(Qb, Kb, Vb, mask, outp);
}

// Round 14
// 145.713 us; speedup vs baseline: 1.2119x; 1.0112x over previous
//
#include <hip/hip_runtime.h>
#include <hip/hip_bf16.h>
#include <stdint.h>

// Problem constants
constexpr int cB = 2;
constexpr int cS = 2048;
constexpr int cH = 1024;
constexpr int cNH = 16;
constexpr int cHD = 64;
constexpr int cBS = cB * cS;  // 4096

typedef short short8 __attribute__((ext_vector_type(8)));
typedef short short4v __attribute__((ext_vector_type(4)));
typedef float f32x4 __attribute__((ext_vector_type(4)));

// HW bf16 convert (RNE)
__device__ inline unsigned short f2bf(float f) {
  __hip_bfloat16 h = __float2bfloat16(f);
  return __builtin_bit_cast(unsigned short, h);
}

__device__ inline void gload_lds16(const void* g, void* l) {
  __builtin_amdgcn_global_load_lds(
      (const __attribute__((address_space(1))) void*)g,
      (__attribute__((address_space(3))) void*)l,
      16, 0, 0);
}

// ds_read_b64_tr_b16 (verified r7): each lane does a plain 64b read (4
// consecutive bf16) at its OWN addr; HW transposes within each 16-lane
// group: the group's reads form a 4x16 tile T (lane s supplies
// T[s>>2][(s&3)*4..+4)); lane a receives column a (elem j = T[j][a]).
__device__ inline short4v tr16(const unsigned short* p) {
  short4v d;
  auto p3 = (const __attribute__((address_space(3))) unsigned short*)p;
  asm volatile("ds_read_b64_tr_b16 %0, %1" : "=v"(d) : "v"(p3) : "memory");
  return d;
}

// One DPP max step: x = max(x, row_ror<CTRL>(x)). CTRL must be a literal.
template <int CTRL>
__device__ inline float dppmax(float x) {
  int v = __builtin_bit_cast(int, x);
  int y = __builtin_amdgcn_update_dpp(0, v, CTRL, 0xf, 0xf, true);
  return fmaxf(x, __builtin_bit_cast(float, y));
}

// 16-lane max reduction on the VALU (DPP row rotates; no DS-pipe traffic).
__device__ inline float rowmax16(float x) {
  x = dppmax<0x121>(x);
  x = dppmax<0x122>(x);
  x = dppmax<0x124>(x);
  x = dppmax<0x128>(x);
  return x;
}

// ---------------- QKV GEMM (unchanged from r10, green) ----------------
constexpr int BM = 128, BN = 128, BK = 32;

__global__ __launch_bounds__(256) void qkv_gemm(
    const float* __restrict__ X,   // [4096][1024]
    const float* __restrict__ Wq,  // [1024][1024] (row=out, col=in)
    const float* __restrict__ Wk,
    const float* __restrict__ Wv,
    const float* __restrict__ bq, const float* __restrict__ bk,
    const float* __restrict__ bv,
    unsigned short* __restrict__ Qb, unsigned short* __restrict__ Kb,
    unsigned short* __restrict__ Vb) {
  __shared__ alignas(16) unsigned short As[BM * BK];  // [128][32]
  __shared__ alignas(16) unsigned short Bs[BN * BK];

  const int nb = blockIdx.x;  // 0..23
  const int mb = blockIdx.y;  // 0..31
  const int m0 = mb * BM;
  const int wsel = nb >> 3;
  const int n0 = (nb & 7) * BN;
  const float* W = (wsel == 0) ? Wq : (wsel == 1 ? Wk : Wv);
  const float* bias = (wsel == 0) ? bq : (wsel == 1 ? bk : bv);
  unsigned short* Out = (wsel == 0) ? Qb : (wsel == 1 ? Kb : Vb);
  const float oscale = (wsel == 0) ? 0.125f : 1.0f;  // fold 1/sqrt(HD) into Q

  const int t = threadIdx.x;
  const int w = t >> 6, l = t & 63, lr = l & 15, lg = l >> 4;
  const int wm = w >> 1, wn = w & 1;
  const int srow = t >> 1;
  const int scol = (t & 1) * 16;

  f32x4 acc[4][4];
#pragma unroll
  for (int mi = 0; mi < 4; ++mi)
#pragma unroll
    for (int ni = 0; ni < 4; ++ni) acc[mi][ni] = {0.f, 0.f, 0.f, 0.f};

  for (int kt = 0; kt < cH / BK; ++kt) {
    const int k0 = kt * BK;
    __syncthreads();
    {
      const float* s = X + (size_t)(m0 + srow) * cH + k0 + scol;
      f32x4 v0 = *reinterpret_cast<const f32x4*>(s);
      f32x4 v1 = *reinterpret_cast<const f32x4*>(s + 4);
      f32x4 v2 = *reinterpret_cast<const f32x4*>(s + 8);
      f32x4 v3 = *reinterpret_cast<const f32x4*>(s + 12);
      short8 o0, o1;
#pragma unroll
      for (int j = 0; j < 4; ++j) {
        o0[j] = (short)f2bf(v0[j]);
        o0[4 + j] = (short)f2bf(v1[j]);
        o1[j] = (short)f2bf(v2[j]);
        o1[4 + j] = (short)f2bf(v3[j]);
      }
      *reinterpret_cast<short8*>(&As[srow * BK + scol]) = o0;
      *reinterpret_cast<short8*>(&As[srow * BK + scol + 8]) = o1;
    }
    {
      const float* s = W + (size_t)(n0 + srow) * cH + k0 + scol;
      f32x4 v0 = *reinterpret_cast<const f32x4*>(s);
      f32x4 v1 = *reinterpret_cast<const f32x4*>(s + 4);
      f32x4 v2 = *reinterpret_cast<const f32x4*>(s + 8);
      f32x4 v3 = *reinterpret_cast<const f32x4*>(s + 12);
      short8 o0, o1;
#pragma unroll
      for (int j = 0; j < 4; ++j) {
        o0[j] = (short)f2bf(v0[j]);
        o0[4 + j] = (short)f2bf(v1[j]);
        o1[j] = (short)f2bf(v2[j]);
        o1[4 + j] = (short)f2bf(v3[j]);
      }
      *reinterpret_cast<short8*>(&Bs[srow * BK + scol]) = o0;
      *reinterpret_cast<short8*>(&Bs[srow * BK + scol + 8]) = o1;
    }
    __syncthreads();

    short8 af[4], bfr[4];
#pragma unroll
    for (int mi = 0; mi < 4; ++mi)
      af[mi] = *reinterpret_cast<const short8*>(
          &As[(wm * 64 + mi * 16 + lr) * BK + lg * 8]);
#pragma unroll
    for (int ni = 0; ni < 4; ++ni)
      bfr[ni] = *reinterpret_cast<const short8*>(
          &Bs[(wn * 64 + ni * 16 + lr) * BK + lg * 8]);
#pragma unroll
    for (int mi = 0; mi < 4; ++mi)
#pragma unroll
      for (int ni = 0; ni < 4; ++ni)
        acc[mi][ni] = __builtin_amdgcn_mfma_f32_16x16x32_bf16(
            af[mi], bfr[ni], acc[mi][ni], 0, 0, 0);
  }

#pragma unroll
  for (int ni = 0; ni < 4; ++ni) {
    const int col = n0 + wn * 64 + ni * 16 + lr;
    const float bvv = bias[col];
#pragma unroll
    for (int mi = 0; mi < 4; ++mi) {
      const int row = m0 + wm * 64 + mi * 16 + lg * 4;
#pragma unroll
      for (int r = 0; r < 4; ++r)
        Out[(size_t)(row + r) * cH + col] =
            f2bf((acc[mi][ni][r] + bvv) * oscale);
    }
  }
}

// ---------------- Flash attention ----------------
// r11 structure: block = (qb, bh) covering 128 q-rows; 4 waves x 32 q-rows
// (2 subtiles of 16). K/V staged once per block; V tr16 frags shared.
// r13: DPP softmax max. r14: defer-rescale (T13, THR=8, wave-uniform skip)
// + batched PV (all 24 tr16 issued, ONE lgkmcnt wait, 40-MFMA cluster).
__global__ __launch_bounds__(256) void attn_kernel(
    const unsigned short* __restrict__ Qb,  // [B*S][H] bf16 (pre-scaled)
    const unsigned short* __restrict__ Kb,
    const unsigned short* __restrict__ Vb,
    const float* __restrict__ mask,         // [B][S]
    float* __restrict__ out) {              // [B*S][H] fp32
  __shared__ alignas(16) unsigned short Ks[2][64 * 64];       // 16 KB
  __shared__ alignas(16) unsigned short Vs[2][64 * 64];       // 16 KB
  __shared__ alignas(16) unsigned short plds[4][2][64 * 16];  // 16 KB

  const int qb = blockIdx.x;  // 0..15
  const int bh = blockIdx.y;  // 0..31
  const int b = bh >> 4, h = bh & 15;
  const int t = threadIdx.x;
  const int w = t >> 6, l = t & 63, lr = l & 15, lg = l >> 4;
  const int q0 = qb * 128 + w * 32;

  const unsigned short* Kbase = Kb + (size_t)b * cS * cH + h * cHD;
  const unsigned short* Vbase = Vb + (size_t)b * cS * cH + h * cHD;
  const float* mbase = mask + b * cS;

  // Staging decode (r7-verified).
  int rK[2], cK[2], rV[2], cV[2];
#pragma unroll
  for (int s2 = 0; s2 < 2; ++s2) {
    const int g = (w * 2 + s2) * 64 + l;
    const int gr = g >> 3, gc = g & 7;
    rK[s2] = gr;
    cK[s2] = (gc ^ (gr & 7)) * 8;
    rV[s2] = (gr >> 2) * 4 + (gc >> 1);
    cV[s2] = (gr & 3) * 16 + (gc & 1) * 8;
  }

  // Q fragments for 2 subtiles
  short8 qf[2][2];
#pragma unroll
  for (int qi = 0; qi < 2; ++qi) {
    const unsigned short* Qrow =
        Qb + (size_t)(b * cS + q0 + qi * 16 + lr) * cH + h * cHD;
    qf[qi][0] = *reinterpret_cast<const short8*>(Qrow + lg * 8);
    qf[qi][1] = *reinterpret_cast<const short8*>(Qrow + 32 + lg * 8);
  }

  short8 ones;
#pragma unroll
  for (int j = 0; j < 8; ++j) ones[j] = (short)0x3F80;

  f32x4 oacc[2][4];
  f32x4 osum[2];
  float mrow[2][4];
#pragma unroll
  for (int qi = 0; qi < 2; ++qi) {
    osum[qi] = {0.f, 0.f, 0.f, 0.f};
#pragma unroll
    for (int d16 = 0; d16 < 4; ++d16) oacc[qi][d16] = {0.f, 0.f, 0.f, 0.f};
#pragma unroll
    for (int r = 0; r < 4; ++r) mrow[qi][r] = -1e30f;
  }

  auto stage = [&](int bufi, int kv0) {
#pragma unroll
    for (int s2 = 0; s2 < 2; ++s2) {
      gload_lds16(Kbase + (size_t)(kv0 + rK[s2]) * cH + cK[s2],
                  (char*)&Ks[bufi][0] + (w * 2 + s2) * 1024);
      gload_lds16(Vbase + (size_t)(kv0 + rV[s2]) * cH + cV[s2],
                  (char*)&Vs[bufi][0] + (w * 2 + s2) * 1024);
    }
  };

  stage(0, 0);
  asm volatile("s_waitcnt vmcnt(0)" ::: "memory");
  __syncthreads();

  unsigned short* pw0 = &plds[w][0][0];
  unsigned short* pw1 = &plds[w][1][0];

  constexpr int NT = cS / 64;  // 32
  for (int kt = 0; kt < NT; ++kt) {
    const int bufi = kt & 1;
    if (kt + 1 < NT) stage(bufi ^ 1, (kt + 1) * 64);

    const unsigned short* Kt = &Ks[bufi][0];
    const unsigned short* Vt = &Vs[bufi][0];
    const int kv0 = kt * 64;

    // mask values (k-indexed; shared by both subtiles)
    float mv[4];
#pragma unroll
    for (int n = 0; n < 4; ++n) mv[n] = mbase[kv0 + n * 16 + lr];

    // ---- QK^T for both subtiles ----
    f32x4 sc[2][4];
#pragma unroll
    for (int n = 0; n < 4; ++n) {
      const int kr = n * 16 + lr;
      const unsigned sw = (unsigned)((kr & 7) << 4);
      const unsigned b0 = ((unsigned)(kr * 128 + lg * 16)) ^ sw;
      const unsigned b1 = ((unsigned)(kr * 128 + 64 + lg * 16)) ^ sw;
      short8 kf0 = *reinterpret_cast<const short8*>((const char*)Kt + b0);
      short8 kf1 = *reinterpret_cast<const short8*>((const char*)Kt + b1);
#pragma unroll
      for (int qi = 0; qi < 2; ++qi) {
        f32x4 z = {0.f, 0.f, 0.f, 0.f};
        z = __builtin_amdgcn_mfma_f32_16x16x32_bf16(qf[qi][0], kf0, z, 0, 0, 0);
        z = __builtin_amdgcn_mfma_f32_16x16x32_bf16(qf[qi][1], kf1, z, 0, 0, 0);
        sc[qi][n] = z + mv[n];
      }
    }

    // ---- online softmax: DPP max; defer-rescale (THR=8, wave-uniform) ----
    float mnew[2][4];
    int ok = 1;
#pragma unroll
    for (int qi = 0; qi < 2; ++qi)
#pragma unroll
      for (int r = 0; r < 4; ++r) {
        float mx = fmaxf(fmaxf(sc[qi][0][r], sc[qi][1][r]),
                         fmaxf(sc[qi][2][r], sc[qi][3][r]));
        mx = rowmax16(mx);
        mnew[qi][r] = fmaxf(mrow[qi][r], mx);
        ok &= (mx - mrow[qi][r] <= 8.0f) ? 1 : 0;
      }
    if (!__all(ok)) {
#pragma unroll
      for (int qi = 0; qi < 2; ++qi) {
#pragma unroll
        for (int r = 0; r < 4; ++r) {
          const float scalef = __expf(mrow[qi][r] - mnew[qi][r]);
          mrow[qi][r] = mnew[qi][r];
          osum[qi][r] *= scalef;
#pragma unroll
          for (int d16 = 0; d16 < 4; ++d16) oacc[qi][d16][r] *= scalef;
        }
      }
    }

    // ---- P = exp(sc - mrow) (bounded by e^8 when deferred), write P^T ----
#pragma unroll
    for (int qi = 0; qi < 2; ++qi) {
      unsigned short* pw = qi ? pw1 : pw0;
      const int pcb = (lg ^ (lr >> 2)) * 4;
#pragma unroll
      for (int n = 0; n < 4; ++n) {
        short4v v4;
#pragma unroll
        for (int r = 0; r < 4; ++r)
          v4[r] = (short)f2bf(__expf(sc[qi][n][r] - mrow[qi][r]));
        *reinterpret_cast<short4v*>(&pw[(n * 16 + lr) * 16 + pcb]) = v4;
      }
    }
    asm volatile("s_waitcnt lgkmcnt(0)" ::: "memory");
    __builtin_amdgcn_sched_barrier(0);

    // ---- PV: issue ALL tr16 (8 P + 16 V), ONE wait, then 40-MFMA cluster ----
    short4v pt[2][4];  // [ks2][t0a,t1a,t0b,t1b]
    short4v tv[2][8];  // [ks2][2*d16+half]
#pragma unroll
    for (int ks2 = 0; ks2 < 2; ++ks2) {
      const int k0 = ks2 * 32 + lg * 8;
      const int key = (lg & 1) * 2;
      pt[ks2][0] = tr16(&pw0[(k0 + (lr >> 2)) * 16 + (((lr & 3) ^ key) * 4)]);
      pt[ks2][1] =
          tr16(&pw0[(k0 + 4 + (lr >> 2)) * 16 + (((lr & 3) ^ key ^ 1) * 4)]);
      pt[ks2][2] = tr16(&pw1[(k0 + (lr >> 2)) * 16 + (((lr & 3) ^ key) * 4)]);
      pt[ks2][3] =
          tr16(&pw1[(k0 + 4 + (lr >> 2)) * 16 + (((lr & 3) ^ key ^ 1) * 4)]);
#pragma unroll
      for (int d16 = 0; d16 < 4; ++d16) {
        const unsigned short* a0 =
            Vt + (ks2 * 8 + lg * 2) * 256 + d16 * 64 + lr * 4;
        tv[ks2][2 * d16] = tr16(a0);
        tv[ks2][2 * d16 + 1] = tr16(a0 + 256);
      }
    }
    asm volatile("s_waitcnt lgkmcnt(0)" ::: "memory");
    __builtin_amdgcn_sched_barrier(0);
#pragma unroll
    for (int ks2 = 0; ks2 < 2; ++ks2) {
      short8 paA, paB;
#pragma unroll
      for (int j = 0; j < 4; ++j) {
        paA[j] = pt[ks2][0][j];
        paA[4 + j] = pt[ks2][1][j];
        paB[j] = pt[ks2][2][j];
        paB[4 + j] = pt[ks2][3][j];
      }
      osum[0] =
          __builtin_amdgcn_mfma_f32_16x16x32_bf16(paA, ones, osum[0], 0, 0, 0);
      osum[1] =
          __builtin_amdgcn_mfma_f32_16x16x32_bf16(paB, ones, osum[1], 0, 0, 0);
#pragma unroll
      for (int d16 = 0; d16 < 4; ++d16) {
        short8 vf;
#pragma unroll
        for (int j = 0; j < 4; ++j) {
          vf[j] = tv[ks2][2 * d16][j];
          vf[4 + j] = tv[ks2][2 * d16 + 1][j];
        }
        oacc[0][d16] = __builtin_amdgcn_mfma_f32_16x16x32_bf16(
            paA, vf, oacc[0][d16], 0, 0, 0);
        oacc[1][d16] = __builtin_amdgcn_mfma_f32_16x16x32_bf16(
            paB, vf, oacc[1][d16], 0, 0, 0);
      }
    }

    asm volatile("s_waitcnt vmcnt(0)" ::: "memory");
    __syncthreads();  // staged tile kt+1 ready; all waves done with buf kt
  }

  // fp32 store; denominator from the MFMA row-sum accumulator
#pragma unroll
  for (int qi = 0; qi < 2; ++qi) {
    float* obase =
        out + (size_t)(b * cS + q0 + qi * 16 + lg * 4) * cH + h * cHD;
#pragma unroll
    for (int r = 0; r < 4; ++r) {
      const float inv = 1.0f / osum[qi][r];
#pragma unroll
      for (int d16 = 0; d16 < 4; ++d16)
        obase[(size_t)r * cH + d16 * 16 + lr] = oacc[qi][d16][r] * inv;
    }
  }
}

// ---------------- launcher ----------------
extern "C" void kernel_launch(void* const* d_in, const int* in_sizes, int n_in,
                              void* d_out, int out_size, void* d_ws,
                              size_t ws_size, hipStream_t stream) {
  const float* X = (const float*)d_in[0];     // [B,S,H]
  const float* mask = (const float*)d_in[1];  // [B,1,1,S]
  const float* Wq = (const float*)d_in[2];
  const float* bq = (const float*)d_in[3];
  const float* Wk = (const float*)d_in[4];
  const float* bk = (const float*)d_in[5];
  const float* Wv = (const float*)d_in[6];
  const float* bv = (const float*)d_in[7];
  float* outp = (float*)d_out;  // fp32 (reference output dtype)

  // workspace: Q,K,V bf16 -> 24 MB total
  char* ws = (char*)d_ws;
  const size_t MB = 1 << 20;
  unsigned short* Qb = (unsigned short*)(ws + 0 * MB);   // 8 MB
  unsigned short* Kb = (unsigned short*)(ws + 8 * MB);   // 8 MB
  unsigned short* Vb = (unsigned short*)(ws + 16 * MB);  // 8 MB

  qkv_gemm<<<dim3(24, 32), 256, 0, stream>>>(X, Wq, Wk, Wv, bq, bk, bv, Qb, Kb,
                                             Vb);
  attn_kernel<<<dim3(16, 32), 256, 0, stream>>>(Qb, Kb, Vb, mask, outp);
}